// Round 13
// baseline (190.200 us; speedup 1.0000x reference)
//
#include <hip/hip_runtime.h>
#include <hip/hip_bf16.h>

// RelationCos pipeline in 3 kernels:
//   K1: FPS (blocks 0-15, packed-u64 argmax + LDS coord table) || W->bf16 packed (16-255)
//   K2: KNN (512 blocks, 8 waves; packed-u64) -> idx in ws
//   K3: gather-fused GEMM, R9 shape (4 queries x 512 cols, grid 512, max B-reuse) +
//       depth-2 issue-early staging pipeline (T14) + 256B-contiguous A gathers.
//       LDS: 4 pair-slabs [64][72] bf16 (2 k-steps each), 2 barriers / 4 k-steps.

#define NPTS 8192
#define SPTS 32
#define KNN_K 12
#define DS 256
#define DT 1024
#define DOUT 1024

typedef float f32x4 __attribute__((ext_vector_type(4)));
typedef __bf16 bf16x8 __attribute__((ext_vector_type(8)));
typedef unsigned short ushort_t;
typedef unsigned long long u64;

__device__ __forceinline__ ushort_t f2bf(float f) {
    unsigned int u = __float_as_uint(f);
    u += 0x7fffu + ((u >> 16) & 1u);   // RNE
    return (ushort_t)(u >> 16);
}

__device__ __forceinline__ ushort4 cvt4(float4 v) {
    ushort4 u;
    u.x = f2bf(v.x); u.y = f2bf(v.y); u.z = f2bf(v.z); u.w = f2bf(v.w);
    return u;
}

// ==================== K1: FPS || W convert (packed) ====================
// Packed layout: element (col,k) -> [k>>5]*(DOUT*32) + col*32 + (k&31)
__global__ __launch_bounds__(512) void fps_convw_kernel(const float* __restrict__ xyz,
                                                        float* __restrict__ new_xyz,
                                                        const float* __restrict__ Wt,
                                                        ushort_t* __restrict__ Wb_t,
                                                        const float* __restrict__ Ws,
                                                        ushort_t* __restrict__ Wb_s) {
    int bid = blockIdx.x;
    int tid = threadIdx.x;

    if (bid >= 16) {
        int lin = (bid - 16) * 512 + tid;
        const int stride = 240 * 512;
        for (int i = lin; i < (DT * DOUT) / 4; i += stride) {   // t: KD=1024
            int col = i >> 8, k4 = i & 255;
            float4 v = reinterpret_cast<const float4*>(Wt)[i];
            size_t off = (size_t)(k4 >> 3) * (DOUT * 32) + col * 32 + (k4 & 7) * 4;
            *reinterpret_cast<ushort4*>(Wb_t + off) = cvt4(v);
        }
        for (int i = lin; i < (DS * DOUT) / 4; i += stride) {   // s: KD=256
            int col = i >> 6, k4 = i & 63;
            float4 v = reinterpret_cast<const float4*>(Ws)[i];
            size_t off = (size_t)(k4 >> 3) * (DOUT * 32) + col * 32 + (k4 & 7) * 4;
            *reinterpret_cast<ushort4*>(Wb_s + off) = cvt4(v);
        }
        return;
    }

    {
#pragma clang fp contract(off)
        int b = bid;
        const float* base = xyz + (size_t)b * NPTS * 3;

        __shared__ float cx[NPTS], cy[NPTS], cz[NPTS];   // 96 KB coord table
        __shared__ u64 rkey[2][8];

        float px[16], py[16], pz[16], dd[16];
#pragma unroll
        for (int i = 0; i < 16; ++i) {
            int p = tid + i * 512;
            px[i] = base[p * 3 + 0];
            py[i] = base[p * 3 + 1];
            pz[i] = base[p * 3 + 2];
            dd[i] = 1e10f;
            cx[p] = px[i]; cy[p] = py[i]; cz[p] = pz[i];
        }

        float lx = base[0], ly = base[1], lz = base[2];
        if (tid == 0) {
            new_xyz[((size_t)b * SPTS + 0) * 3 + 0] = lx;
            new_xyz[((size_t)b * SPTS + 0) * 3 + 1] = ly;
            new_xyz[((size_t)b * SPTS + 0) * 3 + 2] = lz;
        }

        int w = tid >> 6;
        for (int it = 1; it < SPTS; ++it) {
            int par = it & 1;
            u64 bk = 0;
#pragma unroll
            for (int i = 0; i < 16; ++i) {
                float dx = px[i] - lx, dy = py[i] - ly, dz = pz[i] - lz;
                float d = dx * dx + dy * dy;
                d = d + dz * dz;
                float nd = fminf(dd[i], d);
                dd[i] = nd;
                u64 kd = ((u64)__float_as_uint(nd) << 32) | (unsigned)(8191 - (tid + i * 512));
                bk = (kd > bk) ? kd : bk;
            }
#pragma unroll
            for (int off = 1; off < 64; off <<= 1) {
                u64 ok = __shfl_xor(bk, off);
                bk = (ok > bk) ? ok : bk;
            }
            if ((tid & 63) == 0) rkey[par][w] = bk;
            __syncthreads();
            u64 nk = rkey[par][0];
#pragma unroll
            for (int w2 = 1; w2 < 8; ++w2) {
                u64 v2 = rkey[par][w2];
                nk = (v2 > nk) ? v2 : nk;
            }
            int idx = 8191 - (int)(unsigned)(nk & 0xFFFFFFFFull);
            lx = cx[idx]; ly = cy[idx]; lz = cz[idx];
            if (tid == 0) {
                new_xyz[((size_t)b * SPTS + it) * 3 + 0] = lx;
                new_xyz[((size_t)b * SPTS + it) * 3 + 1] = ly;
                new_xyz[((size_t)b * SPTS + it) * 3 + 2] = lz;
            }
        }
    }
}

// ==================== K2: KNN (unchanged, passing) ====================
__global__ __launch_bounds__(512) void knn_kernel(const float* __restrict__ xyz_s,
                                                  const float* __restrict__ xyz_t,
                                                  const float* __restrict__ new_xyz,
                                                  int* __restrict__ idx_s,
                                                  int* __restrict__ idx_t) {
#pragma clang fp contract(off)
    int q = blockIdx.x;
    int tid = threadIdx.x;
    int w = tid >> 6, lane = tid & 63;
    int set = w >> 2;
    int sw = w & 3;
    int b = q >> 5;

    const float* pts = (set ? xyz_t : xyz_s) + (size_t)b * NPTS * 3;

    float qx = new_xyz[q * 3 + 0];
    float qy = new_xyz[q * 3 + 1];
    float qz = new_xyz[q * 3 + 2];
    float qq = qx * qx + qy * qy;
    qq = qq + qz * qz;

    u64 bd[12];
#pragma unroll
    for (int j = 0; j < 12; ++j) bd[j] = ~0ULL;

    for (int i = 0; i < 2048 / 64; ++i) {
        int p = sw * 2048 + i * 64 + lane;
        float p0 = pts[p * 3 + 0], p1 = pts[p * 3 + 1], p2 = pts[p * 3 + 2];
        float pp = p0 * p0 + p1 * p1; pp = pp + p2 * p2;
        float dot = qx * p0 + qy * p1; dot = dot + qz * p2;
        float d = (qq - 2.0f * dot) + pp;
        unsigned u = __float_as_uint(d);
        u = (u & 0x80000000u) ? ~u : (u | 0x80000000u);
        u64 key = ((u64)u << 32) | (unsigned)p;
        if (key < bd[11]) {
#pragma unroll
            for (int j = 11; j > 0; --j) {
                bool keep = (key >= bd[j]);
                u64 sh = (key >= bd[j - 1]) ? key : bd[j - 1];
                bd[j] = keep ? bd[j] : sh;
            }
            if (key < bd[0]) bd[0] = key;
        }
    }

    __shared__ u64 sd[2][48];

#pragma unroll
    for (int r = 0; r < KNN_K; ++r) {
        u64 cv = bd[0];
#pragma unroll
        for (int off = 1; off < 64; off <<= 1) {
            u64 ov = __shfl_xor(cv, off);
            cv = (ov < cv) ? ov : cv;
        }
        if (lane == 0) sd[set][sw * KNN_K + r] = cv;
        if (cv == bd[0]) {
#pragma unroll
            for (int j = 0; j < 11; ++j) bd[j] = bd[j + 1];
            bd[11] = ~0ULL;
        }
    }
    __syncthreads();

    if (sw == 0) {
        int* outp = (set ? idx_t : idx_s) + q * KNN_K;
        u64 cd = (lane < 48) ? sd[set][lane] : ~0ULL;
#pragma unroll
        for (int r = 0; r < KNN_K; ++r) {
            u64 mv = cd;
#pragma unroll
            for (int off = 1; off < 64; off <<= 1) {
                u64 ov = __shfl_xor(mv, off);
                mv = (ov < mv) ? ov : mv;
            }
            if (lane == 0) outp[r] = (int)(unsigned)(mv & 0xFFFFFFFFull);
            if (cd == mv) cd = ~0ULL;
        }
    }
}

// ==================== K3: gather-fused GEMM, 4q x 512cols, depth-2 pipeline ====================
// Pair-slab = 64 rows x 64 k-floats (2 k-steps). Staging: 16 thr/row x float4 = 256B
// contiguous per row per pair; each thread covers rows sr and sr+32. LDS [4][64][72]
// (stride 36 dwords -> 2-way banks, free). Issue pairs {2i+4,2i+5} at superstep i
// start; write {2i+2,2i+3} at superstep i end -> ~2 supersteps of latency cover.
template <int KD>
__device__ __forceinline__ void gemm_body(int qg, int ch, const float* __restrict__ feat,
                                          const int* __restrict__ idx,
                                          const ushort_t* __restrict__ Wb,
                                          const float* __restrict__ bias,
                                          const float* __restrict__ gamma,
                                          const float* __restrict__ beta,
                                          const float* __restrict__ mean,
                                          const float* __restrict__ var,
                                          float* __restrict__ out,
                                          ushort_t (*abuf)[64][72]) {
    const int NK = KD / 32;          // k-steps
    const int NS = KD / 128;         // supersteps (4 k-steps each): t=8, s=2
    int tid = threadIdx.x;
    int w = tid >> 6, lane = tid & 63;
    int lrow = lane & 15, kgrp = lane >> 4;
    int q0 = qg * 4;
    int b = q0 >> 5;

    // staging role: sr = row in [0,32), seg covers 256B/row; rows sr and sr+32
    int sr = tid >> 4, seg = tid & 15;
    int row0 = sr, row1 = sr + 32;
    bool v0 = (row0 & 15) < KNN_K;
    bool v1 = (row1 & 15) < KNN_K;
    int src0 = v0 ? idx[(q0 + (row0 >> 4)) * KNN_K + (row0 & 15)] : 0;
    int src1 = v1 ? idx[(q0 + (row1 >> 4)) * KNN_K + (row1 & 15)] : 0;
    const float* sp0 = feat + ((size_t)b * NPTS + src0) * KD + seg * 4;
    const float* sp1 = feat + ((size_t)b * NPTS + src1) * KD + seg * 4;

    const float4 fz = {0.f, 0.f, 0.f, 0.f};

#define ISSUE(pa, X0, X1, X2, X3)                                              \
    do {                                                                       \
        X0 = v0 ? *reinterpret_cast<const float4*>(sp0 + (pa) * 64) : fz;      \
        X1 = v1 ? *reinterpret_cast<const float4*>(sp1 + (pa) * 64) : fz;      \
        X2 = v0 ? *reinterpret_cast<const float4*>(sp0 + (pa + 1) * 64) : fz;  \
        X3 = v1 ? *reinterpret_cast<const float4*>(sp1 + (pa + 1) * 64) : fz;  \
    } while (0)

#define WRITEP(pa, X0, X1, X2, X3)                                                    \
    do {                                                                              \
        *reinterpret_cast<ushort4*>(&abuf[(pa) & 3][row0][seg * 4]) = cvt4(X0);       \
        *reinterpret_cast<ushort4*>(&abuf[(pa) & 3][row1][seg * 4]) = cvt4(X1);       \
        *reinterpret_cast<ushort4*>(&abuf[(pa + 1) & 3][row0][seg * 4]) = cvt4(X2);   \
        *reinterpret_cast<ushort4*>(&abuf[(pa + 1) & 3][row1][seg * 4]) = cvt4(X3);   \
    } while (0)

    f32x4 acc[4][4];
#pragma unroll
    for (int mf = 0; mf < 4; ++mf)
#pragma unroll
        for (int nf = 0; nf < 4; ++nf) {
            f32x4 z = {0.f, 0.f, 0.f, 0.f};
            acc[mf][nf] = z;
        }

    // prologue: pairs 0,1 direct; issue pairs 2,3 -> set A
    {
        float4 t0, t1, t2, t3;
        ISSUE(0, t0, t1, t2, t3);
        WRITEP(0, t0, t1, t2, t3);
    }
    float4 A0, A1, A2, A3, B0, B1, B2, B3;
    ISSUE(2, A0, A1, A2, A3);
    __syncthreads();

#pragma unroll
    for (int i = 0; i < NS; ++i) {
        // issue loads for superstep i+2 (pairs 2i+4, 2i+5)
        if ((i & 1) == 0) {
            if (i + 2 < NS) ISSUE(2 * i + 4, B0, B1, B2, B3);
        } else {
            if (i + 2 < NS) ISSUE(2 * i + 4, A0, A1, A2, A3);
        }

        // compute 4 k-steps from pairs 2i, 2i+1
#pragma unroll
        for (int kk2 = 0; kk2 < 4; ++kk2) {
            int kk = 4 * i + kk2;
            int pb = (kk >> 1) & 3, hf = kk & 1;
            bf16x8 a[4];
#pragma unroll
            for (int mf = 0; mf < 4; ++mf)
                a[mf] = *reinterpret_cast<const bf16x8*>(
                    &abuf[pb][mf * 16 + lrow][hf * 32 + kgrp * 8]);
#pragma unroll
            for (int nf = 0; nf < 4; ++nf) {
                int col = ch * 512 + w * 64 + nf * 16 + lrow;
                const ushort_t* bp = Wb + (size_t)kk * (DOUT * 32) + (size_t)col * 32 + kgrp * 8;
                bf16x8 bfr = *reinterpret_cast<const bf16x8*>(bp);
#pragma unroll
                for (int mf = 0; mf < 4; ++mf)
                    acc[mf][nf] = __builtin_amdgcn_mfma_f32_16x16x32_bf16(a[mf], bfr, acc[mf][nf], 0, 0, 0);
            }
        }
        __syncthreads();

        // write pairs 2i+2, 2i+3 (issued 2 supersteps ago)
        if (i + 1 < NS) {
            if ((i & 1) == 0) WRITEP(2 * i + 2, A0, A1, A2, A3);
            else              WRITEP(2 * i + 2, B0, B1, B2, B3);
            __syncthreads();
        }
    }
#undef ISSUE
#undef WRITEP

    // epilogue: BN + ReLU + max over rows 0..11 (frag rows = kgrp*4+e; kgrp==3 pads)
#pragma unroll
    for (int nf = 0; nf < 4; ++nf) {
        int col = ch * 512 + w * 64 + nf * 16 + lrow;
        float sc = gamma[col] / sqrtf(var[col] + 1e-5f);
        float sh = (bias[col] - mean[col]) * sc + beta[col];
#pragma unroll
        for (int mf = 0; mf < 4; ++mf) {
            float m;
            if (kgrp < 3) {
                float y0 = fmaxf(acc[mf][nf][0] * sc + sh, 0.0f);
                float y1 = fmaxf(acc[mf][nf][1] * sc + sh, 0.0f);
                float y2 = fmaxf(acc[mf][nf][2] * sc + sh, 0.0f);
                float y3 = fmaxf(acc[mf][nf][3] * sc + sh, 0.0f);
                m = fmaxf(fmaxf(y0, y1), fmaxf(y2, y3));
            } else {
                m = -1e30f;
            }
            m = fmaxf(m, __shfl_xor(m, 16));
            m = fmaxf(m, __shfl_xor(m, 32));
            if (kgrp == 0) out[(size_t)(q0 + mf) * DOUT + col] = m;
        }
    }
}

struct GP {
    const float* feature_s; const float* feature_t;
    const int* idx_s; const int* idx_t;
    const ushort_t* Wb_s; const ushort_t* Wb_t;
    const float* bias_s; const float* gamma_s; const float* beta_s;
    const float* mean_s; const float* var_s;
    const float* bias_t; const float* gamma_t; const float* beta_t;
    const float* mean_t; const float* var_t;
    float* out;
};

__global__ __launch_bounds__(512, 4) void gemm_kernel(GP P) {
    __shared__ ushort_t abuf[4][64][72];   // 36.9 KB
    int bid = blockIdx.x;
    bool is_t = (bid < 256);               // heavy t tasks dispatch first
    int r2 = is_t ? bid : bid - 256;
    int qg = r2 >> 1, ch = r2 & 1;         // 128 query-groups x 2 col-halves
    if (is_t) {
        gemm_body<DT>(qg, ch, P.feature_t, P.idx_t, P.Wb_t, P.bias_t, P.gamma_t,
                      P.beta_t, P.mean_t, P.var_t, P.out + (size_t)512 * 1024, abuf);
    } else {
        gemm_body<DS>(qg, ch, P.feature_s, P.idx_s, P.Wb_s, P.bias_s, P.gamma_s,
                      P.beta_s, P.mean_s, P.var_s, P.out, abuf);
    }
}

extern "C" void kernel_launch(void* const* d_in, const int* in_sizes, int n_in,
                              void* d_out, int out_size, void* d_ws, size_t ws_size,
                              hipStream_t stream) {
    const float* feature_s = (const float*)d_in[0];
    const float* xyz_s     = (const float*)d_in[1];
    const float* feature_t = (const float*)d_in[2];
    const float* xyz_t     = (const float*)d_in[3];
    const float* Ws        = (const float*)d_in[4];
    const float* Wt        = (const float*)d_in[10];
    float* out = (float*)d_out;

    char* ws = (char*)d_ws;
    float* new_xyz  = (float*)(ws + 0);
    int* idx_s      = (int*)(ws + 8192);
    int* idx_t      = (int*)(ws + 32768);
    ushort_t* Wb_s  = (ushort_t*)(ws + 57344);
    ushort_t* Wb_t  = (ushort_t*)(ws + 581632);

    fps_convw_kernel<<<256, 512, 0, stream>>>(xyz_t, new_xyz, Wt, Wb_t, Ws, Wb_s);
    knn_kernel<<<512, 512, 0, stream>>>(xyz_s, xyz_t, new_xyz, idx_s, idx_t);

    GP P;
    P.feature_s = feature_s; P.feature_t = feature_t;
    P.idx_s = idx_s; P.idx_t = idx_t;
    P.Wb_s = Wb_s; P.Wb_t = Wb_t;
    P.bias_s = (const float*)d_in[5];  P.gamma_s = (const float*)d_in[6];
    P.beta_s = (const float*)d_in[7];  P.mean_s  = (const float*)d_in[8];
    P.var_s  = (const float*)d_in[9];
    P.bias_t = (const float*)d_in[11]; P.gamma_t = (const float*)d_in[12];
    P.beta_t = (const float*)d_in[13]; P.mean_t  = (const float*)d_in[14];
    P.var_t  = (const float*)d_in[15];
    P.out = out;

    gemm_kernel<<<512, 512, 0, stream>>>(P);
}

// Round 14
// 119.136 us; speedup vs baseline: 1.5965x; 1.5965x over previous
//
#include <hip/hip_runtime.h>
#include <hip/hip_bf16.h>

// RelationCos pipeline in 3 kernels:
//   K1: FPS (blocks 0-15, packed-u64 argmax + LDS coord table) || W->bf16 packed (16-255)
//   K2: KNN (512 blocks, 8 waves; packed-u64) -> idx in ws
//   K3: gather-fused GEMM, R9 shape (4 queries x 512 cols, grid 512) but with
//       32x32x16 MFMA: 8 MFMA + 8 loads per K=32 per wave (was 16+8) -> fewer
//       instructions & matrix cycles. LDS [2][64][44] double-buffer, 1 barrier/k-step.

#define NPTS 8192
#define SPTS 32
#define KNN_K 12
#define DS 256
#define DT 1024
#define DOUT 1024

typedef float f32x4 __attribute__((ext_vector_type(4)));
typedef float f32x16 __attribute__((ext_vector_type(16)));
typedef __bf16 bf16x8 __attribute__((ext_vector_type(8)));
typedef unsigned short ushort_t;
typedef unsigned long long u64;

__device__ __forceinline__ ushort_t f2bf(float f) {
    unsigned int u = __float_as_uint(f);
    u += 0x7fffu + ((u >> 16) & 1u);   // RNE
    return (ushort_t)(u >> 16);
}

__device__ __forceinline__ ushort4 cvt4(float4 v) {
    ushort4 u;
    u.x = f2bf(v.x); u.y = f2bf(v.y); u.z = f2bf(v.z); u.w = f2bf(v.w);
    return u;
}

// ==================== K1: FPS || W convert (packed) ====================
// Packed layout: element (col,k) -> [k>>5]*(DOUT*32) + col*32 + (k&31)
__global__ __launch_bounds__(512) void fps_convw_kernel(const float* __restrict__ xyz,
                                                        float* __restrict__ new_xyz,
                                                        const float* __restrict__ Wt,
                                                        ushort_t* __restrict__ Wb_t,
                                                        const float* __restrict__ Ws,
                                                        ushort_t* __restrict__ Wb_s) {
    int bid = blockIdx.x;
    int tid = threadIdx.x;

    if (bid >= 16) {
        int lin = (bid - 16) * 512 + tid;
        const int stride = 240 * 512;
        for (int i = lin; i < (DT * DOUT) / 4; i += stride) {   // t: KD=1024
            int col = i >> 8, k4 = i & 255;
            float4 v = reinterpret_cast<const float4*>(Wt)[i];
            size_t off = (size_t)(k4 >> 3) * (DOUT * 32) + col * 32 + (k4 & 7) * 4;
            *reinterpret_cast<ushort4*>(Wb_t + off) = cvt4(v);
        }
        for (int i = lin; i < (DS * DOUT) / 4; i += stride) {   // s: KD=256
            int col = i >> 6, k4 = i & 63;
            float4 v = reinterpret_cast<const float4*>(Ws)[i];
            size_t off = (size_t)(k4 >> 3) * (DOUT * 32) + col * 32 + (k4 & 7) * 4;
            *reinterpret_cast<ushort4*>(Wb_s + off) = cvt4(v);
        }
        return;
    }

    {
#pragma clang fp contract(off)
        int b = bid;
        const float* base = xyz + (size_t)b * NPTS * 3;

        __shared__ float cx[NPTS], cy[NPTS], cz[NPTS];   // 96 KB coord table
        __shared__ u64 rkey[2][8];

        float px[16], py[16], pz[16], dd[16];
#pragma unroll
        for (int i = 0; i < 16; ++i) {
            int p = tid + i * 512;
            px[i] = base[p * 3 + 0];
            py[i] = base[p * 3 + 1];
            pz[i] = base[p * 3 + 2];
            dd[i] = 1e10f;
            cx[p] = px[i]; cy[p] = py[i]; cz[p] = pz[i];
        }

        float lx = base[0], ly = base[1], lz = base[2];
        if (tid == 0) {
            new_xyz[((size_t)b * SPTS + 0) * 3 + 0] = lx;
            new_xyz[((size_t)b * SPTS + 0) * 3 + 1] = ly;
            new_xyz[((size_t)b * SPTS + 0) * 3 + 2] = lz;
        }

        int w = tid >> 6;
        for (int it = 1; it < SPTS; ++it) {
            int par = it & 1;
            u64 bk = 0;
#pragma unroll
            for (int i = 0; i < 16; ++i) {
                float dx = px[i] - lx, dy = py[i] - ly, dz = pz[i] - lz;
                float d = dx * dx + dy * dy;
                d = d + dz * dz;
                float nd = fminf(dd[i], d);
                dd[i] = nd;
                u64 kd = ((u64)__float_as_uint(nd) << 32) | (unsigned)(8191 - (tid + i * 512));
                bk = (kd > bk) ? kd : bk;
            }
#pragma unroll
            for (int off = 1; off < 64; off <<= 1) {
                u64 ok = __shfl_xor(bk, off);
                bk = (ok > bk) ? ok : bk;
            }
            if ((tid & 63) == 0) rkey[par][w] = bk;
            __syncthreads();
            u64 nk = rkey[par][0];
#pragma unroll
            for (int w2 = 1; w2 < 8; ++w2) {
                u64 v2 = rkey[par][w2];
                nk = (v2 > nk) ? v2 : nk;
            }
            int idx = 8191 - (int)(unsigned)(nk & 0xFFFFFFFFull);
            lx = cx[idx]; ly = cy[idx]; lz = cz[idx];
            if (tid == 0) {
                new_xyz[((size_t)b * SPTS + it) * 3 + 0] = lx;
                new_xyz[((size_t)b * SPTS + it) * 3 + 1] = ly;
                new_xyz[((size_t)b * SPTS + it) * 3 + 2] = lz;
            }
        }
    }
}

// ==================== K2: KNN (unchanged, passing) ====================
__global__ __launch_bounds__(512) void knn_kernel(const float* __restrict__ xyz_s,
                                                  const float* __restrict__ xyz_t,
                                                  const float* __restrict__ new_xyz,
                                                  int* __restrict__ idx_s,
                                                  int* __restrict__ idx_t) {
#pragma clang fp contract(off)
    int q = blockIdx.x;
    int tid = threadIdx.x;
    int w = tid >> 6, lane = tid & 63;
    int set = w >> 2;
    int sw = w & 3;
    int b = q >> 5;

    const float* pts = (set ? xyz_t : xyz_s) + (size_t)b * NPTS * 3;

    float qx = new_xyz[q * 3 + 0];
    float qy = new_xyz[q * 3 + 1];
    float qz = new_xyz[q * 3 + 2];
    float qq = qx * qx + qy * qy;
    qq = qq + qz * qz;

    u64 bd[12];
#pragma unroll
    for (int j = 0; j < 12; ++j) bd[j] = ~0ULL;

    for (int i = 0; i < 2048 / 64; ++i) {
        int p = sw * 2048 + i * 64 + lane;
        float p0 = pts[p * 3 + 0], p1 = pts[p * 3 + 1], p2 = pts[p * 3 + 2];
        float pp = p0 * p0 + p1 * p1; pp = pp + p2 * p2;
        float dot = qx * p0 + qy * p1; dot = dot + qz * p2;
        float d = (qq - 2.0f * dot) + pp;
        unsigned u = __float_as_uint(d);
        u = (u & 0x80000000u) ? ~u : (u | 0x80000000u);
        u64 key = ((u64)u << 32) | (unsigned)p;
        if (key < bd[11]) {
#pragma unroll
            for (int j = 11; j > 0; --j) {
                bool keep = (key >= bd[j]);
                u64 sh = (key >= bd[j - 1]) ? key : bd[j - 1];
                bd[j] = keep ? bd[j] : sh;
            }
            if (key < bd[0]) bd[0] = key;
        }
    }

    __shared__ u64 sd[2][48];

#pragma unroll
    for (int r = 0; r < KNN_K; ++r) {
        u64 cv = bd[0];
#pragma unroll
        for (int off = 1; off < 64; off <<= 1) {
            u64 ov = __shfl_xor(cv, off);
            cv = (ov < cv) ? ov : cv;
        }
        if (lane == 0) sd[set][sw * KNN_K + r] = cv;
        if (cv == bd[0]) {
#pragma unroll
            for (int j = 0; j < 11; ++j) bd[j] = bd[j + 1];
            bd[11] = ~0ULL;
        }
    }
    __syncthreads();

    if (sw == 0) {
        int* outp = (set ? idx_t : idx_s) + q * KNN_K;
        u64 cd = (lane < 48) ? sd[set][lane] : ~0ULL;
#pragma unroll
        for (int r = 0; r < KNN_K; ++r) {
            u64 mv = cd;
#pragma unroll
            for (int off = 1; off < 64; off <<= 1) {
                u64 ov = __shfl_xor(mv, off);
                mv = (ov < mv) ? ov : mv;
            }
            if (lane == 0) outp[r] = (int)(unsigned)(mv & 0xFFFFFFFFull);
            if (cd == mv) cd = ~0ULL;
        }
    }
}

// ==================== K3: gather-fused GEMM, 32x32x16 MFMA ====================
// Block = 4 queries (64 rows = 2 m-frags of 32) x 512 cols; 8 waves, 64 cols/wave
// (2 n-frags of 32). Per K=32 step: 4 a-frag LDS reads + 4 B loads + 8 MFMA.
// A frag: row=lane&31, k=(lane>>5)*8+e. B frag: col=lane&31, same k (from packed Wb).
// C/D (m74/m101): col=lane&31, row=(reg&3)+8*(reg>>2)+4*(lane>>5).
// LDS [2][64][44] dbuf (stride 22 words -> 2-way banks, free), 1 barrier/k-step.
template <int KD>
__device__ __forceinline__ void gemm_body(int qg, int ch, const float* __restrict__ feat,
                                          const int* __restrict__ idx,
                                          const ushort_t* __restrict__ Wb,
                                          const float* __restrict__ bias,
                                          const float* __restrict__ gamma,
                                          const float* __restrict__ beta,
                                          const float* __restrict__ mean,
                                          const float* __restrict__ var,
                                          float* __restrict__ out,
                                          ushort_t (*abuf)[64][44]) {
    const int NK = KD / 32;
    int tid = threadIdx.x;
    int w = tid >> 6, lane = tid & 63;
    int l31 = lane & 31, hi = lane >> 5;
    int q0 = qg * 4;
    int b = q0 >> 5;

    // staging role: 8 threads per row, one float4 (16B) each
    int r = tid >> 3, seg = tid & 7;
    int sk = r & 15;
    bool valid = (sk < KNN_K);
    int src = valid ? idx[(q0 + (r >> 4)) * KNN_K + sk] : 0;
    const float* srcp = feat + ((size_t)b * NPTS + src) * KD + seg * 4;

    f32x16 acc[2][2];
#pragma unroll
    for (int mf = 0; mf < 2; ++mf)
#pragma unroll
        for (int nf = 0; nf < 2; ++nf)
            acc[mf][nf] = (f32x16)(0.0f);

    const float4 fz = {0.f, 0.f, 0.f, 0.f};

    // prologue: stage slab 0
    {
        float4 v = valid ? *reinterpret_cast<const float4*>(srcp) : fz;
        *reinterpret_cast<ushort4*>(&abuf[0][r][seg * 4]) = cvt4(v);
    }
    __syncthreads();

    for (int kk = 0; kk < NK; ++kk) {
        int cur = kk & 1;
        float4 nv = fz;
        if (kk + 1 < NK && valid)
            nv = *reinterpret_cast<const float4*>(srcp + (kk + 1) * 32);

        // A frags: rows mf*32 + l31; k-half h: offset h*16 + hi*8
        bf16x8 a[2][2];
#pragma unroll
        for (int mf = 0; mf < 2; ++mf)
#pragma unroll
            for (int h = 0; h < 2; ++h)
                a[mf][h] = *reinterpret_cast<const bf16x8*>(
                    &abuf[cur][mf * 32 + l31][h * 16 + hi * 8]);

        // B frags from packed Wb: col = colbase + nf*32 + l31, k&31 = h*16 + hi*8
#pragma unroll
        for (int h = 0; h < 2; ++h) {
#pragma unroll
            for (int nf = 0; nf < 2; ++nf) {
                int col = ch * 512 + w * 64 + nf * 32 + l31;
                const ushort_t* bp = Wb + (size_t)kk * (DOUT * 32) + (size_t)col * 32 + h * 16 + hi * 8;
                bf16x8 bfr = *reinterpret_cast<const bf16x8*>(bp);
#pragma unroll
                for (int mf = 0; mf < 2; ++mf)
                    acc[mf][nf] = __builtin_amdgcn_mfma_f32_32x32x16_bf16(a[mf][h], bfr, acc[mf][nf], 0, 0, 0);
            }
        }

        if (kk + 1 < NK)
            *reinterpret_cast<ushort4*>(&abuf[cur ^ 1][r][seg * 4]) = cvt4(nv);
        __syncthreads();
    }

    // epilogue: BN + ReLU + max over k-rows 0..11.
    // reg->row: r = (reg&3) + 8*(reg>>2) + 4*hi. regs 0..7 = query mf*2+0, 8..15 = mf*2+1.
    // krow = r&15: regs (0..3|8..11): 0..3 +4hi (valid); regs (4..7|12..15): 8..11 (hi=0)
    // or 12..15 (hi=1, INVALID).
#pragma unroll
    for (int nf = 0; nf < 2; ++nf) {
        int col = ch * 512 + w * 64 + nf * 32 + l31;
        float sc = gamma[col] / sqrtf(var[col] + 1e-5f);
        float sh = (bias[col] - mean[col]) * sc + beta[col];
#pragma unroll
        for (int mf = 0; mf < 2; ++mf) {
            float mA = -1e30f, mB = -1e30f;
#pragma unroll
            for (int reg = 0; reg < 4; ++reg) {
                mA = fmaxf(mA, fmaxf(acc[mf][nf][reg] * sc + sh, 0.0f));
                mB = fmaxf(mB, fmaxf(acc[mf][nf][reg + 8] * sc + sh, 0.0f));
            }
            if (hi == 0) {
#pragma unroll
                for (int reg = 4; reg < 8; ++reg) {
                    mA = fmaxf(mA, fmaxf(acc[mf][nf][reg] * sc + sh, 0.0f));
                    mB = fmaxf(mB, fmaxf(acc[mf][nf][reg + 8] * sc + sh, 0.0f));
                }
            }
            mA = fmaxf(mA, __shfl_xor(mA, 32));
            mB = fmaxf(mB, __shfl_xor(mB, 32));
            if (hi == 0) {
                out[(size_t)(q0 + mf * 2 + 0) * DOUT + col] = mA;
                out[(size_t)(q0 + mf * 2 + 1) * DOUT + col] = mB;
            }
        }
    }
}

struct GP {
    const float* feature_s; const float* feature_t;
    const int* idx_s; const int* idx_t;
    const ushort_t* Wb_s; const ushort_t* Wb_t;
    const float* bias_s; const float* gamma_s; const float* beta_s;
    const float* mean_s; const float* var_s;
    const float* bias_t; const float* gamma_t; const float* beta_t;
    const float* mean_t; const float* var_t;
    float* out;
};

__global__ __launch_bounds__(512, 4) void gemm_kernel(GP P) {
    __shared__ ushort_t abuf[2][64][44];   // 11.3 KB
    int bid = blockIdx.x;
    bool is_t = (bid < 256);               // heavy t tasks dispatch first
    int r2 = is_t ? bid : bid - 256;
    int qg = r2 >> 1, ch = r2 & 1;         // 128 query-groups x 2 col-halves
    if (is_t) {
        gemm_body<DT>(qg, ch, P.feature_t, P.idx_t, P.Wb_t, P.bias_t, P.gamma_t,
                      P.beta_t, P.mean_t, P.var_t, P.out + (size_t)512 * 1024, abuf);
    } else {
        gemm_body<DS>(qg, ch, P.feature_s, P.idx_s, P.Wb_s, P.bias_s, P.gamma_s,
                      P.beta_s, P.mean_s, P.var_s, P.out, abuf);
    }
}

extern "C" void kernel_launch(void* const* d_in, const int* in_sizes, int n_in,
                              void* d_out, int out_size, void* d_ws, size_t ws_size,
                              hipStream_t stream) {
    const float* feature_s = (const float*)d_in[0];
    const float* xyz_s     = (const float*)d_in[1];
    const float* feature_t = (const float*)d_in[2];
    const float* xyz_t     = (const float*)d_in[3];
    const float* Ws        = (const float*)d_in[4];
    const float* Wt        = (const float*)d_in[10];
    float* out = (float*)d_out;

    char* ws = (char*)d_ws;
    float* new_xyz  = (float*)(ws + 0);
    int* idx_s      = (int*)(ws + 8192);
    int* idx_t      = (int*)(ws + 32768);
    ushort_t* Wb_s  = (ushort_t*)(ws + 57344);
    ushort_t* Wb_t  = (ushort_t*)(ws + 581632);

    fps_convw_kernel<<<256, 512, 0, stream>>>(xyz_t, new_xyz, Wt, Wb_t, Ws, Wb_s);
    knn_kernel<<<512, 512, 0, stream>>>(xyz_s, xyz_t, new_xyz, idx_s, idx_t);

    GP P;
    P.feature_s = feature_s; P.feature_t = feature_t;
    P.idx_s = idx_s; P.idx_t = idx_t;
    P.Wb_s = Wb_s; P.Wb_t = Wb_t;
    P.bias_s = (const float*)d_in[5];  P.gamma_s = (const float*)d_in[6];
    P.beta_s = (const float*)d_in[7];  P.mean_s  = (const float*)d_in[8];
    P.var_s  = (const float*)d_in[9];
    P.bias_t = (const float*)d_in[11]; P.gamma_t = (const float*)d_in[12];
    P.beta_t = (const float*)d_in[13]; P.mean_t  = (const float*)d_in[14];
    P.var_t  = (const float*)d_in[15];
    P.out = out;

    gemm_kernel<<<512, 512, 0, stream>>>(P);
}